// Round 15
// baseline (276.945 us; speedup 1.0000x reference)
//
#include <hip/hip_runtime.h>

typedef unsigned int u32;
typedef unsigned short u16;
typedef __attribute__((ext_vector_type(4))) float f32x4;
typedef __attribute__((ext_vector_type(8))) short bf16x8;
typedef __attribute__((ext_vector_type(4))) u32 u32x4;

__device__ __forceinline__ u16 f2bf(float f) {
  u32 u = __builtin_bit_cast(u32, f);
  u = u + 0x7FFFu + ((u >> 16) & 1u);
  return (u16)(u >> 16);
}
__device__ __forceinline__ u32 pack2(float a, float b) {
  return (u32)f2bf(a) | ((u32)f2bf(b) << 16);
}
// Pack two C-frags (f32x4 each) into one A/B-frag under the consistent
// k-permutation sigma(8g+p) = 16*(p>>2) + g*4 + (p&3) (+32*kb outside).
// Valid because BOTH operands of the attention-middle MFMAs share sigma.
__device__ __forceinline__ bf16x8 pack8(f32x4 a, f32x4 b) {
  union { u32 w[4]; bf16x8 v; } u;
  u.w[0] = pack2(a[0], a[1]); u.w[1] = pack2(a[2], a[3]);
  u.w[2] = pack2(b[0], b[1]); u.w[3] = pack2(b[2], b[3]);
  return u.v;
}

#define MFMA(a, b, c) __builtin_amdgcn_mfma_f32_16x16x32_bf16((a), (b), (c), 0, 0, 0)

// LDS fragment read: row-major buffer, XOR-swizzled within 128B window.
__device__ __forceinline__ bf16x8 lds_frag(const char* buf, int rowBytes, int row, int kByte) {
  return *(const bf16x8*)(buf + row * rowBytes + (kByte ^ ((row & 7) << 4)));
}

// window/token -> flat token index in [B,32,32,32] (C-contiguous per token)
__device__ __forceinline__ int tok_global(int blk, int t) {
  int b = blk >> 9, r = blk & 511;
  int wd = r >> 6, wh = (r >> 3) & 7, ww = r & 7;
  int d = wd * 4 + (t >> 4);
  int h = wh * 4 + ((t >> 2) & 3);
  int w = ww * 4 + (t & 3);
  return ((b * 32 + d) * 32 + h) * 32 + w;
}

// Weights -> FRAG-MAJOR blob, NATURAL k order within each 32-chunk:
// w[(o_blk*16 + ks)*512 + lane*8 + p] = bf16 of W[ks*32 + g*8 + p][o_blk*16 + lr],
// lane = g*16 + lr. Wave frag load = base + lane*8 -> 1KB contiguous.
__global__ void prep_weights(const float* __restrict__ wq, const float* __restrict__ wp,
                             u16* __restrict__ wtq, u16* __restrict__ wtp) {
  int idx = blockIdx.x * 512 + threadIdx.x;
  if (idx < 512 * 1536) {
    int i = idx / 1536, o = idx % 1536;     // coalesced read of W_qkv[i][o]
    int c = i & 31;                          // k-local, natural order
    int lane = (c >> 3) * 16 + (o & 15);
    wtq[((size_t)(o >> 4) * 16 + (i >> 5)) * 512 + lane * 8 + (c & 7)] = f2bf(wq[idx]);
  } else {
    int j = idx - 512 * 1536;
    int i = j >> 9, o = j & 511;
    int c = i & 31;
    int lane = (c >> 3) * 16 + (o & 15);
    wtp[((size_t)(o >> 4) * 16 + (i >> 5)) * 512 + lane * 8 + (c & 7)] = f2bf(wp[j]);
  }
}

// Async-stage one K-step's 32KB weight chunk (32 o_blks x 1KB, verbatim)
// into LDS via global_load_lds (16B/lane, wave-uniform dest + lane*16).
__device__ __forceinline__ void stage_w(const char* Wb, char* wbuf, int ks, int tid) {
#pragma unroll
  for (int r = 0; r < 4; ++r) {
    const int flat = r * 8192 + tid * 16;            // 0..32767, lane-contiguous
    const char* src = Wb + ((size_t)((flat >> 10) * 16 + ks) << 10) + (flat & 1023);
    __builtin_amdgcn_global_load_lds((const u32*)src, (u32*)(wbuf + flat), 16, 0, 0);
  }
}

// m97-style K-loop: async-stage ks+1 while computing ks from LDS; one
// vmcnt(0)+barrier per step. Weight frag = contiguous ds_read_b128.
#define GEMM_PASS_AB(WB)                                                      \
  {                                                                           \
    stage_w((WB), wb0, 0, tid);                                               \
    asm volatile("s_waitcnt vmcnt(0)" ::: "memory");                          \
    __syncthreads();                                                          \
    _Pragma("unroll") for (int ks = 0; ks < 16; ++ks) {                       \
      if (ks < 15) stage_w((WB), (ks & 1) ? wb0 : wb1, ks + 1, tid);          \
      char* wb = (ks & 1) ? wb1 : wb0;                                        \
      bf16x8 bx[4], wf[4];                                                    \
      const int kByte = ks * 64 + g * 16;                                     \
      _Pragma("unroll") for (int j = 0; j < 4; ++j)                           \
          bx[j] = lds_frag(smem, 1024, j * 16 + lr, kByte);                   \
      _Pragma("unroll") for (int i = 0; i < 4; ++i)                           \
          wf[i] = *(const bf16x8*)(wb + (wv * 4 + i) * 1024 + l * 16);        \
      __builtin_amdgcn_s_setprio(1);                                          \
      _Pragma("unroll") for (int i = 0; i < 4; ++i)                           \
        _Pragma("unroll") for (int j = 0; j < 4; ++j)                         \
            acc[i][j] = MFMA(wf[i], bx[j], acc[i][j]);                        \
      __builtin_amdgcn_s_setprio(0);                                          \
      asm volatile("s_waitcnt vmcnt(0)" ::: "memory");                        \
      __syncthreads();                                                        \
    }                                                                         \
  }
#define GEMM_PASS_BA(WB)                                                      \
  {                                                                           \
    stage_w((WB), wb0, 0, tid);                                               \
    asm volatile("s_waitcnt vmcnt(0)" ::: "memory");                          \
    __syncthreads();                                                          \
    _Pragma("unroll") for (int ks = 0; ks < 16; ++ks) {                       \
      if (ks < 15) stage_w((WB), (ks & 1) ? wb0 : wb1, ks + 1, tid);          \
      char* wb = (ks & 1) ? wb1 : wb0;                                        \
      bf16x8 bx[4], wf[4];                                                    \
      const int kByte = ks * 64 + g * 16;                                     \
      _Pragma("unroll") for (int j = 0; j < 4; ++j)                           \
          bx[j] = lds_frag(smem, 1024, j * 16 + lr, kByte);                   \
      _Pragma("unroll") for (int i = 0; i < 4; ++i)                           \
          wf[i] = *(const bf16x8*)(wb + (wv * 4 + i) * 1024 + l * 16);        \
      __builtin_amdgcn_s_setprio(1);                                          \
      _Pragma("unroll") for (int i = 0; i < 4; ++i)                           \
        _Pragma("unroll") for (int j = 0; j < 4; ++j)                         \
            acc[i][j] = MFMA(bx[i], wf[j], acc[i][j]);                        \
      __builtin_amdgcn_s_setprio(0);                                          \
      asm volatile("s_waitcnt vmcnt(0)" ::: "memory");                        \
      __syncthreads();                                                        \
    }                                                                         \
  }

__global__ __launch_bounds__(512, 2) void fused_win_attn(
    const float* __restrict__ x, const float* __restrict__ bq, const float* __restrict__ bp,
    const u16* __restrict__ wtq, const u16* __restrict__ wtp, float* __restrict__ out) {
  // LDS: [0,64K) x [64 tok][512 ch] bf16 swizzled (-> O, -> Y-staging later);
  //      [64K,96K) + [96K,128K): double-buffered 32KB weight chunks (DMA).
  __shared__ char smem[131072];
  char* wb0 = smem + 65536;
  char* wb1 = smem + 98304;
  const int tid = threadIdx.x;
  const int wv = tid >> 6;   // wave id == head id
  const int l  = tid & 63;
  const int lr = l & 15;
  const int g  = l >> 4;
  const int blk = blockIdx.x;

  // ---- stage x -> LDS bf16 (once; 1 barrier) ----
  {
    const int st = tid >> 3, seg = tid & 7;       // token row, 64-ch segment
    const float* xs = x + (size_t)tok_global(blk, st) * 512 + seg * 64;
    char* dst = smem + st * 1024;
    const int swz = (st & 7) << 4;
    float4 f[16];
#pragma unroll
    for (int i = 0; i < 16; ++i) f[i] = ((const float4*)xs)[i];
#pragma unroll
    for (int i = 0; i < 8; ++i) {
      const int ic = (i + seg) & 7;   // rotate across bank quads per phase
      u32x4 w = {pack2(f[2 * ic].x, f[2 * ic].y),         pack2(f[2 * ic].z, f[2 * ic].w),
                 pack2(f[2 * ic + 1].x, f[2 * ic + 1].y), pack2(f[2 * ic + 1].z, f[2 * ic + 1].w)};
      *(u32x4*)(dst + ((seg * 128 + ic * 16) ^ swz)) = w;
    }
  }
  __syncthreads();

  // pass base pointers into the frag-major blobs (chunk c = wv*4 + i)
  const char* WQ = (const char*)wtq;                 // o_blks 0..31
  const char* WK = WQ + 524288;                      // o_blks 32..63
  const char* WV = WQ + 1048576;                     // o_blks 64..95
  const char* WP = (const char*)wtp;                 // proj o_blks 0..31

  bf16x8 qp[4][2], ka[4][2], pb[4][2], va[4][2];
  f32x4 acc[4][4];

  // ======== Q pass: Q [d=64][t=64] (M=och, N=t, K=ch 512) ========
#pragma unroll
  for (int i = 0; i < 4; ++i)
#pragma unroll
    for (int j = 0; j < 4; ++j) acc[i][j] = (f32x4)0.f;
  GEMM_PASS_AB(WQ);
#pragma unroll
  for (int i = 0; i < 4; ++i) {
    const int och = wv * 64 + i * 16 + g * 4;
    f32x4 qb = {bq[och], bq[och + 1], bq[och + 2], bq[och + 3]};
#pragma unroll
    for (int j = 0; j < 4; ++j) acc[i][j] += qb;
  }
#pragma unroll
  for (int j = 0; j < 4; ++j)
#pragma unroll
    for (int kb = 0; kb < 2; ++kb)
      qp[j][kb] = pack8(acc[2 * kb][j], acc[2 * kb + 1][j]);   // B-frag: col t, k=d

  // ======== K pass ========
#pragma unroll
  for (int i = 0; i < 4; ++i)
#pragma unroll
    for (int j = 0; j < 4; ++j) acc[i][j] = (f32x4)0.f;
  GEMM_PASS_AB(WK);
#pragma unroll
  for (int i = 0; i < 4; ++i) {
    const int och = 512 + wv * 64 + i * 16 + g * 4;
    f32x4 kb = {bq[och], bq[och + 1], bq[och + 2], bq[och + 3]};
#pragma unroll
    for (int j = 0; j < 4; ++j) acc[i][j] += kb;
  }
#pragma unroll
  for (int m = 0; m < 4; ++m)
#pragma unroll
    for (int kb = 0; kb < 2; ++kb)
      ka[m][kb] = pack8(acc[2 * kb][m], acc[2 * kb + 1][m]);   // A-frag: row s, k=d

  // ======== S^T = K-rows x Q (M=s, N=t, K=d=64): pure register MFMA ========
  {
    f32x4 sacc[4][4];
#pragma unroll
    for (int m = 0; m < 4; ++m)
#pragma unroll
      for (int j = 0; j < 4; ++j) {
        f32x4 a = (f32x4)0.f;
        a = MFMA(ka[m][0], qp[j][0], a);
        sacc[m][j] = MFMA(ka[m][1], qp[j][1], a);
      }
    // scale + clip + softmax over s (16 local + xor16 + xor32)
#pragma unroll
    for (int m = 0; m < 4; ++m)
#pragma unroll
      for (int j = 0; j < 4; ++j)
#pragma unroll
        for (int r = 0; r < 4; ++r) {
          float v = sacc[m][j][r] * 0.125f;
          sacc[m][j][r] = fminf(fmaxf(v, -10000.f), 10000.f);
        }
    float mx[4], sm[4];
#pragma unroll
    for (int j = 0; j < 4; ++j) {
      float a0 = fmaxf(fmaxf(sacc[0][j][0], sacc[0][j][1]), fmaxf(sacc[0][j][2], sacc[0][j][3]));
      float a1 = fmaxf(fmaxf(sacc[1][j][0], sacc[1][j][1]), fmaxf(sacc[1][j][2], sacc[1][j][3]));
      float a2 = fmaxf(fmaxf(sacc[2][j][0], sacc[2][j][1]), fmaxf(sacc[2][j][2], sacc[2][j][3]));
      float a3 = fmaxf(fmaxf(sacc[3][j][0], sacc[3][j][1]), fmaxf(sacc[3][j][2], sacc[3][j][3]));
      mx[j] = fmaxf(fmaxf(a0, a1), fmaxf(a2, a3));
    }
#pragma unroll
    for (int j = 0; j < 4; ++j) mx[j] = fmaxf(mx[j], __shfl_xor(mx[j], 16));
#pragma unroll
    for (int j = 0; j < 4; ++j) mx[j] = fmaxf(mx[j], __shfl_xor(mx[j], 32));
#pragma unroll
    for (int j = 0; j < 4; ++j) {
      float s0 = 0.f;
#pragma unroll
      for (int m = 0; m < 4; ++m)
#pragma unroll
        for (int r = 0; r < 4; ++r) {
          float p = __expf(sacc[m][j][r] - mx[j]);
          sacc[m][j][r] = p;
          s0 += p;
        }
      sm[j] = s0;
    }
#pragma unroll
    for (int j = 0; j < 4; ++j) sm[j] += __shfl_xor(sm[j], 16);
#pragma unroll
    for (int j = 0; j < 4; ++j) sm[j] += __shfl_xor(sm[j], 32);
#pragma unroll
    for (int j = 0; j < 4; ++j) {
      float inv = 1.f / sm[j];
#pragma unroll
      for (int kb = 0; kb < 2; ++kb)
        pb[j][kb] = pack8(sacc[2 * kb][j] * inv, sacc[2 * kb + 1][j] * inv);  // B-frag
    }
  }

  // ======== V pass: V [s=64][d=64] (M=t(=s), N=d, K=ch 512) ========
#pragma unroll
  for (int i = 0; i < 4; ++i)
#pragma unroll
    for (int j = 0; j < 4; ++j) acc[i][j] = (f32x4)0.f;
  GEMM_PASS_BA(WV);
#pragma unroll
  for (int ni = 0; ni < 4; ++ni) {
    float bv = bq[1024 + wv * 64 + ni * 16 + lr];
#pragma unroll
    for (int ti = 0; ti < 4; ++ti) acc[ti][ni] += (f32x4)bv;
#pragma unroll
    for (int kb = 0; kb < 2; ++kb)
      va[ni][kb] = pack8(acc[2 * kb][ni], acc[2 * kb + 1][ni]);  // A-frag: row d, k=s
  }

  // ---- all x reads done; switch LDS[0,64K) to O [t][512] bf16 ----
  __syncthreads();

  // ======== O^T = V^T x P^T (M=d, N=t, K=s=64) + write O to LDS ========
#pragma unroll
  for (int ni = 0; ni < 4; ++ni)
#pragma unroll
    for (int j = 0; j < 4; ++j) {
      f32x4 a = (f32x4)0.f;
      a = MFMA(va[ni][0], pb[j][0], a);
      a = MFMA(va[ni][1], pb[j][1], a);
      int t = j * 16 + lr;
      int cb = (wv * 64 + ni * 16 + g * 4) * 2;
      int swz = (t & 7) << 4;
      *(u32*)(smem + t * 1024 + (cb ^ swz))       = pack2(a[0], a[1]);
      *(u32*)(smem + t * 1024 + ((cb + 4) ^ swz)) = pack2(a[2], a[3]);
    }
  __syncthreads();

  // ======== Y = O @ Wproj (M=och, N=t, K=ch 512) ========
#pragma unroll
  for (int i = 0; i < 4; ++i)
#pragma unroll
    for (int j = 0; j < 4; ++j) acc[i][j] = (f32x4)0.f;
  GEMM_PASS_AB(WP);
  // +bias into acc
#pragma unroll
  for (int mi = 0; mi < 4; ++mi) {
    const int och = wv * 64 + mi * 16 + g * 4;
    f32x4 bb = {bp[och], bp[och + 1], bp[och + 2], bp[och + 3]};
#pragma unroll
    for (int tj = 0; tj < 4; ++tj) acc[mi][tj] += bb;
  }

  // ======== Epilogue: stage Y via LDS, fully coalesced f32 stores ========
  // Two halves of 32 tokens; LDS[0,64K) as [32 tok][512 och] f32, XOR-swizzled.
#pragma unroll
  for (int th = 0; th < 2; ++th) {
    __syncthreads();   // th=0: all waves done reading O; th=1: done reading half 0
#pragma unroll
    for (int mi = 0; mi < 4; ++mi)
#pragma unroll
      for (int jj = 0; jj < 2; ++jj) {
        const int tj = th * 2 + jj;
        const int tl = (tj * 16 + lr) & 31;                 // token within half
        const int ochb = (wv * 64 + mi * 16 + g * 4) * 4;   // byte offset of och
        *(f32x4*)(smem + tl * 2048 + (ochb ^ ((tl & 7) << 4))) = acc[mi][tj];
      }
    __syncthreads();
    // store: each wave-iteration writes 1KB contiguous (half a token's channels)
#pragma unroll
    for (int it = 0; it < 8; ++it) {
      const int task = it * 8 + wv;       // 0..63
      const int tl = task >> 1;           // 0..31
      const int hf = task & 1;            // which 1KB half of the 2KB token row
      const int ochb = hf * 1024 + l * 16;
      f32x4 v = *(const f32x4*)(smem + tl * 2048 + (ochb ^ ((tl & 7) << 4)));
      *(f32x4*)(out + (size_t)tok_global(blk, th * 32 + tl) * 512 + hf * 256 + l * 4) = v;
    }
  }
}

extern "C" void kernel_launch(void* const* d_in, const int* in_sizes, int n_in,
                              void* d_out, int out_size, void* d_ws, size_t ws_size,
                              hipStream_t stream) {
  const float* x  = (const float*)d_in[0];
  const float* wq = (const float*)d_in[1];
  const float* bq = (const float*)d_in[2];
  const float* wp = (const float*)d_in[3];
  const float* bp = (const float*)d_in[4];
  float* out = (float*)d_out;
  u16* wtq = (u16*)d_ws;            // qkv frag-major blob: 96 o_blks x 16 ks x 512
  u16* wtp = wtq + 512 * 1536;      // proj frag-major blob: 32 o_blks x 16 ks x 512

  prep_weights<<<2048, 512, 0, stream>>>(wq, wp, wtq, wtp);
  fused_win_attn<<<1024, 512, 0, stream>>>(x, bq, bp, wtq, wtp, out);
}